// Round 1
// baseline (579.054 us; speedup 1.0000x reference)
//
#include <hip/hip_runtime.h>
#include <math.h>

#define NPTS 4096
#define KNN  20
#define NOUT 64
#define BLK  256
#define PT   16   // candidates per thread = NPTS/BLK

__global__ __launch_bounds__(BLK) void edgeconv_kernel(
    const float* __restrict__ x,      // (B, 3, N)
    const float* __restrict__ Wm,     // (64, 6)
    const float* __restrict__ gamma,  // (64)
    const float* __restrict__ beta,   // (64)
    const float* __restrict__ mean,   // (64)
    const float* __restrict__ var,    // (64)
    float* __restrict__ out)          // (B, 64, N)
{
    const int bid = blockIdx.x;
    const int b = bid >> 12;          // N = 4096
    const int n = bid & (NPTS - 1);
    const int t = threadIdx.x;

    __shared__ float swv[4];
    __shared__ int   swi[4];
    __shared__ int   topi[KNN];
    __shared__ float red[BLK];

    const float* xb = x + (size_t)b * 3 * NPTS;
    const float p0 = xb[n];
    const float p1 = xb[NPTS + n];
    const float p2 = xb[2 * NPTS + n];
    const float xxp = p0 * p0 + p1 * p1 + p2 * p2;

    // ---- phase 1: distances for this thread's 16 contiguous candidates ----
    float d[PT];
    const int m0 = t * PT;
    {
        const float4* X0 = (const float4*)(xb + m0);
        const float4* X1 = (const float4*)(xb + NPTS + m0);
        const float4* X2 = (const float4*)(xb + 2 * NPTS + m0);
        #pragma unroll
        for (int j4 = 0; j4 < PT / 4; ++j4) {
            float4 a = X0[j4], bb = X1[j4], cc = X2[j4];
            d[j4*4+0] = 2.f*(p0*a.x + p1*bb.x + p2*cc.x) - xxp - (a.x*a.x + bb.x*bb.x + cc.x*cc.x);
            d[j4*4+1] = 2.f*(p0*a.y + p1*bb.y + p2*cc.y) - xxp - (a.y*a.y + bb.y*bb.y + cc.y*cc.y);
            d[j4*4+2] = 2.f*(p0*a.z + p1*bb.z + p2*cc.z) - xxp - (a.z*a.z + bb.z*bb.z + cc.z*cc.z);
            d[j4*4+3] = 2.f*(p0*a.w + p1*bb.w + p2*cc.w) - xxp - (a.w*a.w + bb.w*bb.w + cc.w*cc.w);
        }
    }

    // cached thread-local best (max value, lowest index on tie)
    float bv = d[0]; int bslot = 0;
    #pragma unroll
    for (int j = 1; j < PT; ++j)
        if (d[j] > bv) { bv = d[j]; bslot = j; }
    int bi = m0 + bslot;

    // ---- phase 2: 20 extraction rounds ----
    for (int r = 0; r < KNN; ++r) {
        // wave butterfly reduce on (val, idx), tie -> lower idx
        float rv = bv; int ri = bi;
        #pragma unroll
        for (int s = 32; s > 0; s >>= 1) {
            float ov = __shfl_xor(rv, s, 64);
            int   oi = __shfl_xor(ri, s, 64);
            if (ov > rv || (ov == rv && oi < ri)) { rv = ov; ri = oi; }
        }
        const int wid = t >> 6;
        if ((t & 63) == 0) { swv[wid] = rv; swi[wid] = ri; }
        __syncthreads();
        // every thread reduces the 4 wave winners (redundant, no 2nd barrier round-trip)
        float gv = swv[0]; int gi = swi[0];
        #pragma unroll
        for (int w = 1; w < 4; ++w) {
            float ov = swv[w]; int oi = swi[w];
            if (ov > gv || (ov == gv && oi < gi)) { gv = ov; gi = oi; }
        }
        if (t == 0) topi[r] = gi;
        // owner thread removes the winner and rescans its 16 registers
        if ((gi >> 4) == t) {
            const int slot = gi & (PT - 1);
            #pragma unroll
            for (int j = 0; j < PT; ++j)
                if (j == slot) d[j] = -INFINITY;
            bv = d[0]; bslot = 0;
            #pragma unroll
            for (int j = 1; j < PT; ++j)
                if (d[j] > bv) { bv = d[j]; bslot = j; }
            bi = m0 + bslot;
        }
        __syncthreads();   // protect swv/swi reuse next round, and topi visibility
    }

    // ---- phase 3: edge linear (6->64) + BN + LeakyReLU + max over K ----
    const int o  = t & 63;
    const int kg = t >> 6;
    const float iv   = gamma[o] / sqrtf(var[o] + 1e-5f);
    const float bias = beta[o] - mean[o] * iv;
    const float* Wr = Wm + o * 6;
    const float wt0 = Wr[0], wt1 = Wr[1], wt2 = Wr[2];
    const float wt3 = Wr[3], wt4 = Wr[4], wt5 = Wr[5];
    const float base = wt3 * p0 + wt4 * p1 + wt5 * p2;

    float best = -INFINITY;
    for (int k = kg; k < KNN; k += 4) {
        const int gi = topi[k];
        const float f0 = xb[gi];
        const float f1 = xb[NPTS + gi];
        const float f2 = xb[2 * NPTS + gi];
        float y = base + wt0 * (f0 - p0) + wt1 * (f1 - p1) + wt2 * (f2 - p2);
        y = y * iv + bias;
        y = (y >= 0.f) ? y : 0.2f * y;
        best = fmaxf(best, y);
    }
    red[t] = best;
    __syncthreads();
    if (t < 64) {
        float m = fmaxf(fmaxf(red[t], red[t + 64]), fmaxf(red[t + 128], red[t + 192]));
        out[((size_t)b * NOUT + o) * NPTS + n] = m;
    }
}

extern "C" void kernel_launch(void* const* d_in, const int* in_sizes, int n_in,
                              void* d_out, int out_size, void* d_ws, size_t ws_size,
                              hipStream_t stream) {
    const float* x     = (const float*)d_in[0];
    const float* Wm    = (const float*)d_in[1];
    const float* gamma = (const float*)d_in[2];
    const float* beta  = (const float*)d_in[3];
    const float* mean  = (const float*)d_in[4];
    const float* var   = (const float*)d_in[5];
    float* out = (float*)d_out;

    const int B = in_sizes[0] / (3 * NPTS);   // 8
    dim3 grid(B * NPTS);
    dim3 block(BLK);
    edgeconv_kernel<<<grid, block, 0, stream>>>(x, Wm, gamma, beta, mean, var, out);
}

// Round 2
// 194.958 us; speedup vs baseline: 2.9701x; 2.9701x over previous
//
#include <hip/hip_runtime.h>
#include <math.h>

#define NPTS 4096
#define KNN  20
#define NOUT 64
#define BLK  256
#define PT   16    // candidates per thread
#define CAP  2048  // LDS candidate-pool capacity (never exceeded for non-degenerate data)

// monotone float->uint map (total order preserved)
__device__ __forceinline__ unsigned ord32(float f) {
    unsigned u = __float_as_uint(f);
    int m = ((int)u) >> 31;
    return u ^ ((unsigned)m | 0x80000000u);
}

__global__ __launch_bounds__(BLK) void edgeconv_kernel(
    const float* __restrict__ x,      // (B, 3, N)
    const float* __restrict__ Wm,     // (64, 6)
    const float* __restrict__ gamma,
    const float* __restrict__ beta,
    const float* __restrict__ mean,
    const float* __restrict__ var,
    float* __restrict__ out)          // (B, 64, N)
{
    const int bid = blockIdx.x;
    const int b = bid >> 12;          // N = 4096
    const int n = bid & (NPTS - 1);
    const int t = threadIdx.x;
    const int lane = t & 63;
    const int wid  = t >> 6;

    __shared__ unsigned long long S[CAP];
    __shared__ unsigned wT[4];
    __shared__ int scnt;
    __shared__ int topi[KNN];
    __shared__ float red[BLK];

    const float* xb = x + (size_t)b * 3 * NPTS;
    const float p0 = xb[n];
    const float p1 = xb[NPTS + n];
    const float p2 = xb[2 * NPTS + n];
    const float xxp = p0 * p0 + p1 * p1 + p2 * p2;

    // ---- phase 1: ordered distance keys for 16 contiguous candidates ----
    unsigned dord[PT];
    const int m0 = t * PT;
    {
        const float4* X0 = (const float4*)(xb + m0);
        const float4* X1 = (const float4*)(xb + NPTS + m0);
        const float4* X2 = (const float4*)(xb + 2 * NPTS + m0);
        #pragma unroll
        for (int j4 = 0; j4 < PT / 4; ++j4) {
            float4 a = X0[j4], bb = X1[j4], cc = X2[j4];
            float d0 = 2.f*(p0*a.x + p1*bb.x + p2*cc.x) - xxp - (a.x*a.x + bb.x*bb.x + cc.x*cc.x);
            float d1 = 2.f*(p0*a.y + p1*bb.y + p2*cc.y) - xxp - (a.y*a.y + bb.y*bb.y + cc.y*cc.y);
            float d2 = 2.f*(p0*a.z + p1*bb.z + p2*cc.z) - xxp - (a.z*a.z + bb.z*bb.z + cc.z*cc.z);
            float d3 = 2.f*(p0*a.w + p1*bb.w + p2*cc.w) - xxp - (a.w*a.w + bb.w*bb.w + cc.w*cc.w);
            dord[j4*4+0] = ord32(d0);
            dord[j4*4+1] = ord32(d1);
            dord[j4*4+2] = ord32(d2);
            dord[j4*4+3] = ord32(d3);
        }
    }

    // ---- phase 2a: threshold = min over waves of (5th-largest lane-max) ----
    unsigned vmax = dord[0];
    #pragma unroll
    for (int j = 1; j < PT; ++j) vmax = max(vmax, dord[j]);

    {   // per-wave bitonic sort (descending) of the 64 lane maxima
        unsigned v = vmax;
        #pragma unroll
        for (int k = 2; k <= 64; k <<= 1) {
            #pragma unroll
            for (int j = k >> 1; j > 0; j >>= 1) {
                unsigned o = __shfl_xor(v, j, 64);
                bool iLower = (lane & j) == 0;
                bool ascB   = (lane & k) != 0;   // inverted -> descending final order
                unsigned mn = min(v, o), mx = max(v, o);
                v = (iLower == ascB) ? mn : mx;
            }
        }
        if (lane == 4) wT[wid] = v;   // 5th largest in this wave
    }
    if (t == 0) scnt = 0;
    __syncthreads();

    const unsigned T = min(min(wT[0], wT[1]), min(wT[2], wT[3]));

    // ---- phase 2b: compact candidates >= T into LDS pool (packed keys) ----
    #pragma unroll
    for (int j = 0; j < PT; ++j) {
        if (dord[j] >= T) {
            int pos = atomicAdd(&scnt, 1);
            if (pos < CAP) {
                int idx = m0 + j;
                S[pos] = ((unsigned long long)dord[j] << 32) |
                         (unsigned)((NPTS - 1) - idx);   // tie -> lower idx wins
            }
        }
    }
    __syncthreads();

    int cnt = scnt; if (cnt > CAP) cnt = CAP;

    // ---- phase 2c: wave 0 selects exact top-20 from the pool ----
    if (wid == 0) {
        if (cnt <= 64) {
            // bitonic sort 64 u64 keys (descending); lanes 0..19 = top-20
            unsigned long long key = (lane < cnt) ? S[lane] : 0ull;
            #pragma unroll
            for (int k = 2; k <= 64; k <<= 1) {
                #pragma unroll
                for (int j = k >> 1; j > 0; j >>= 1) {
                    unsigned long long o = __shfl_xor(key, j, 64);
                    bool iLower = (lane & j) == 0;
                    bool ascB   = (lane & k) != 0;
                    unsigned long long mn = (key < o) ? key : o;
                    unsigned long long mx = (key < o) ? o : key;
                    key = (iLower == ascB) ? mn : mx;
                }
            }
            if (lane < KNN)
                topi[lane] = (NPTS - 1) - (int)(unsigned)(key & 0xFFFFFFFFull);
        } else {
            // rare fallback: 20 extraction rounds, wave-local, LDS rescan
            for (int r = 0; r < KNN; ++r) {
                unsigned long long bk = 0ull; int bp = -1;
                for (int i = lane; i < cnt; i += 64) {
                    unsigned long long kk = S[i];
                    if (kk > bk) { bk = kk; bp = i; }
                }
                unsigned long long rb = bk;
                #pragma unroll
                for (int s = 32; s > 0; s >>= 1) {
                    unsigned long long o = __shfl_xor(rb, s, 64);
                    if (o > rb) rb = o;
                }
                if (bk == rb && bp >= 0) S[bp] = 0ull;  // unique keys -> one owner
                if (lane == 0)
                    topi[r] = (NPTS - 1) - (int)(unsigned)(rb & 0xFFFFFFFFull);
            }
        }
    }
    __syncthreads();

    // ---- phase 3: edge linear (6->64) + BN + LeakyReLU + max over K ----
    const int o  = t & 63;
    const int kg = t >> 6;
    const float iv   = gamma[o] / sqrtf(var[o] + 1e-5f);
    const float bias = beta[o] - mean[o] * iv;
    const float* Wr = Wm + o * 6;
    const float wt0 = Wr[0], wt1 = Wr[1], wt2 = Wr[2];
    const float wt3 = Wr[3], wt4 = Wr[4], wt5 = Wr[5];
    const float base = wt3 * p0 + wt4 * p1 + wt5 * p2;

    float best = -INFINITY;
    for (int k = kg; k < KNN; k += 4) {
        const int gi = topi[k];
        const float f0 = xb[gi];
        const float f1 = xb[NPTS + gi];
        const float f2 = xb[2 * NPTS + gi];
        float y = base + wt0 * (f0 - p0) + wt1 * (f1 - p1) + wt2 * (f2 - p2);
        y = y * iv + bias;
        y = (y >= 0.f) ? y : 0.2f * y;
        best = fmaxf(best, y);
    }
    red[t] = best;
    __syncthreads();
    if (t < 64) {
        float m = fmaxf(fmaxf(red[t], red[t + 64]), fmaxf(red[t + 128], red[t + 192]));
        out[((size_t)b * NOUT + o) * NPTS + n] = m;
    }
}

extern "C" void kernel_launch(void* const* d_in, const int* in_sizes, int n_in,
                              void* d_out, int out_size, void* d_ws, size_t ws_size,
                              hipStream_t stream) {
    const float* x     = (const float*)d_in[0];
    const float* Wm    = (const float*)d_in[1];
    const float* gamma = (const float*)d_in[2];
    const float* beta  = (const float*)d_in[3];
    const float* mean  = (const float*)d_in[4];
    const float* var   = (const float*)d_in[5];
    float* out = (float*)d_out;

    const int B = in_sizes[0] / (3 * NPTS);   // 8
    dim3 grid(B * NPTS);
    dim3 block(BLK);
    edgeconv_kernel<<<grid, block, 0, stream>>>(x, Wm, gamma, beta, mean, var, out);
}